// Round 12
// baseline (171.074 us; speedup 1.0000x reference)
//
#include <hip/hip_runtime.h>
#include <stdint.h>

#define BB 8
#define TTN 4096
#define CCH 32
#define WIN 128
#define KEEP_LT9 3435974144u   // keep iff bits < this (uniform < 0.8f)

typedef __attribute__((ext_vector_type(8))) short bf16x8;
typedef __attribute__((ext_vector_type(4))) float f32x4;

union B8 { uint32_t u[4]; uint4 q; bf16x8 v; };

__device__ __forceinline__ uint32_t cvt_pk_bf16(float lo, float hi) {
    uint32_t d;
    asm("v_cvt_pk_bf16_f32 %0, %1, %2" : "=v"(d) : "v"(lo), "v"(hi));
    return d;
}

// rotl via funnel-shift: 1 VALU inst
__device__ __forceinline__ uint32_t rotl32(uint32_t x, int r) {
    return __builtin_amdgcn_alignbit(x, x, 32 - r);
}

// 4 interleaved threefry2x32 chains (explicit ILP; key (0,42); out = o0^o1)
__device__ __forceinline__ void threefry4(uint32_t i0, uint32_t i1, uint32_t i2, uint32_t i3,
                                          uint32_t& o0, uint32_t& o1, uint32_t& o2, uint32_t& o3) {
    const uint32_t K2 = 42u ^ 0x1BD11BDAu;
    uint32_t a0 = 0u, a1 = 0u, a2 = 0u, a3 = 0u;
    uint32_t b0 = i0 + 42u, b1 = i1 + 42u, b2 = i2 + 42u, b3 = i3 + 42u;
#define R4(r)                                                                  \
    { a0 += b0; a1 += b1; a2 += b2; a3 += b3;                                  \
      b0 = rotl32(b0, (r)); b1 = rotl32(b1, (r));                              \
      b2 = rotl32(b2, (r)); b3 = rotl32(b3, (r));                              \
      b0 ^= a0; b1 ^= a1; b2 ^= a2; b3 ^= a3; }
#define INJ(da, db)                                                            \
    { a0 += (da); a1 += (da); a2 += (da); a3 += (da);                          \
      b0 += (db); b1 += (db); b2 += (db); b3 += (db); }
    R4(13) R4(15) R4(26) R4(6)
    INJ(42u, K2 + 1u)
    R4(17) R4(29) R4(16) R4(24)
    INJ(K2, 2u)
    R4(13) R4(15) R4(26) R4(6)
    INJ(0u, 42u + 3u)
    R4(17) R4(29) R4(16) R4(24)
    INJ(42u, K2 + 4u)
    R4(13) R4(15) R4(26) R4(6)
    INJ(K2, 5u)
#undef R4
#undef INJ
    o0 = a0 ^ b0; o1 = a1 ^ b1; o2 = a2 ^ b2; o3 = a3 ^ b3;
}

// ---------------- projections: Q fp32 (scaled), K bf16 row-major, V bf16 TRANSPOSED ----------------
__global__ __launch_bounds__(256) void proj_qkv(const float* __restrict__ x,
                                                const float* __restrict__ Wq,
                                                const float* __restrict__ Wk,
                                                const float* __restrict__ Wv,
                                                float* __restrict__ Qf,
                                                uint16_t* __restrict__ Kb,
                                                uint16_t* __restrict__ Vt) {
    __shared__ float sW[3][CCH * CCH];
    __shared__ uint16_t vs[256][34];            // v bf16, padded row (bank spread)
    const int tid = threadIdx.x;
    for (int i = tid; i < CCH * CCH; i += 256) {
        sW[0][i] = Wq[i]; sW[1][i] = Wk[i]; sW[2][i] = Wv[i];
    }
    __syncthreads();
    const int row = blockIdx.x * 256 + tid;     // b*T + t
    const float4* xp = reinterpret_cast<const float4*>(x + (size_t)row * CCH);
    float xr[CCH];
    #pragma unroll
    for (int i = 0; i < 8; ++i) {
        float4 t4 = xp[i];
        xr[4*i] = t4.x; xr[4*i+1] = t4.y; xr[4*i+2] = t4.z; xr[4*i+3] = t4.w;
    }
    const float scale = 0.17677669529663687f;   // 1/sqrt(32)
    #pragma unroll
    for (int mtx = 0; mtx < 3; ++mtx) {
        float o[CCH];
        #pragma unroll
        for (int d = 0; d < CCH; ++d) {
            float s0 = 0.f, s1 = 0.f, s2 = 0.f, s3 = 0.f;
            #pragma unroll
            for (int c = 0; c < CCH; c += 4) {
                s0 += xr[c]   * sW[mtx][d*CCH + c];
                s1 += xr[c+1] * sW[mtx][d*CCH + c+1];
                s2 += xr[c+2] * sW[mtx][d*CCH + c+2];
                s3 += xr[c+3] * sW[mtx][d*CCH + c+3];
            }
            o[d] = (s0 + s1) + (s2 + s3);
            if (mtx == 0) o[d] *= scale;
        }
        if (mtx == 0) {
            float4* op = reinterpret_cast<float4*>(Qf + (size_t)row * CCH);
            #pragma unroll
            for (int i = 0; i < 8; ++i)
                op[i] = make_float4(o[4*i], o[4*i+1], o[4*i+2], o[4*i+3]);
        } else if (mtx == 1) {
            uint32_t dw[16];
            #pragma unroll
            for (int k = 0; k < 16; ++k) dw[k] = cvt_pk_bf16(o[2*k], o[2*k+1]);
            uint4* kp = reinterpret_cast<uint4*>((char*)Kb + (size_t)row * 64);
            #pragma unroll
            for (int q = 0; q < 4; ++q)
                kp[q] = make_uint4(dw[4*q], dw[4*q+1], dw[4*q+2], dw[4*q+3]);
        } else {
            #pragma unroll
            for (int k = 0; k < 16; ++k)
                *reinterpret_cast<uint32_t*>(&vs[tid][2*k]) = cvt_pk_bf16(o[2*k], o[2*k+1]);
        }
    }
    __syncthreads();
    // transpose-out: Vt[b][d][4096] bf16; block covers s-range [seg*256, +255] of batch b
    const int b = blockIdx.x >> 4, seg = blockIdx.x & 15;
    const int d = tid >> 3, part = tid & 7;
    uint32_t dw[16];
    #pragma unroll
    for (int k = 0; k < 16; ++k) {
        const uint32_t lo = vs[part*32 + 2*k][d];
        const uint32_t hi = vs[part*32 + 2*k + 1][d];
        dw[k] = lo | (hi << 16);
    }
    uint16_t* dst = Vt + (size_t)b * (CCH * TTN) + (size_t)d * TTN + seg * 256 + part * 32;
    uint4* dp = reinterpret_cast<uint4*>(dst);
    #pragma unroll
    for (int q = 0; q < 4; ++q)
        dp[q] = make_uint4(dw[4*q], dw[4*q+1], dw[4*q+2], dw[4*q+3]);
}

// ---------------- MFMA flash attention, fused threefry, small blocks + backfill ----------------
// Block = 256 thr (4 waves = 4 s-slices of 32 within a 128-s window) covering
// 16 q-rows: b = j&7 (XCD-local K/V), thalf = (j>>3)&1, tile = 127-(j>>4) (LPT,
// big first). 2048 blocks, ~8 resident/CU (VGPR<=64, LDS 4.9KB) -> HW backfill
// kills the R11 drain problem. Per wave-window: direct-global fragment loads ->
// threefry4 x2 (hides L2 latency) -> mfma S^T -> online softmax -> dropout
// select -> P->bf16 -> shfl redistribute -> mfma O^T. Merge = 2-stage LDS tree.
__global__ __launch_bounds__(256, 8) void attn_mfma(const float* __restrict__ Qf,
                                                    const uint16_t* __restrict__ Kb,
                                                    const uint16_t* __restrict__ Vt,
                                                    float* __restrict__ out) {
    __shared__ __align__(16) char smem[4864];   // 2 merge slots

    const int j = blockIdx.x;
    const int b = j & 7;                        // XCD-local batch
    const int thalf = (j >> 3) & 1;
    const int tile = 127 - (j >> 4);            // LPT: biggest tiles first

    const int w = threadIdx.x >> 6;             // wave = s-slice 0..3
    const int lane = threadIdx.x & 63;
    const int tl = lane & 15;
    const int g = lane >> 4;
    const int sg = w;
    const int slb = sg * 32;
    const int tbase = tile * 32 + thalf * 16;   // first of this block's 16 rows
    const int t_g = tbase + tl;

    // Q fragment (B-operand: col=t=lane&15, k=d=8g+j), bf16, loaded once
    const float* qrow = Qf + ((size_t)b * TTN + t_g) * CCH + g * 8;
    const float4 qa = *reinterpret_cast<const float4*>(qrow);
    const float4 qb = *reinterpret_cast<const float4*>(qrow + 4);
    B8 qf;
    qf.u[0] = cvt_pk_bf16(qa.x, qa.y); qf.u[1] = cvt_pk_bf16(qa.z, qa.w);
    qf.u[2] = cvt_pk_bf16(qb.x, qb.y); qf.u[3] = cvt_pk_bf16(qb.z, qb.w);

    f32x4 acc0 = {0.f,0.f,0.f,0.f}, acc1 = {0.f,0.f,0.f,0.f};
    float m = -1e30f, l = 0.f;

    const char* Kbb = (const char*)Kb + (size_t)b * TTN * 64;         // bf16 rows, 64B
    const char* Vbb = (const char*)Vt + (size_t)b * CCH * TTN * 2;    // bf16 [32][4096]
    const uint32_t idxb = ((uint32_t)b << 24) | ((uint32_t)t_g << 12);

    const int nwin = ((tbase + 15) >> 7) + 1;   // windows covering s <= tbase+15

#define ATT_WINDOW(S0, TAIL)                                                   \
    {                                                                          \
        const int srow = (S0) + slb;                                           \
        B8 ka, kc, va, vc, pf;                                                 \
        ka.q = *reinterpret_cast<const uint4*>(Kbb + (size_t)(srow + tl) * 64 + g * 16); \
        kc.q = *reinterpret_cast<const uint4*>(Kbb + (size_t)(srow + 16 + tl) * 64 + g * 16); \
        va.q = *reinterpret_cast<const uint4*>(Vbb + (size_t)tl * 8192 + (size_t)(srow + g * 8) * 2); \
        vc.q = *reinterpret_cast<const uint4*>(Vbb + (size_t)(16 + tl) * 8192 + (size_t)(srow + g * 8) * 2); \
        /* threefry first: ~1150 cy of pure VALU hides the L2 latency */       \
        const uint32_t ib = idxb | (uint32_t)(srow + 4 * g);                   \
        uint32_t r0, r1, r2, r3, r4, r5, r6, r7;                               \
        threefry4(ib,       ib + 1u,  ib + 2u,  ib + 3u,  r0, r1, r2, r3);     \
        threefry4(ib + 16u, ib + 17u, ib + 18u, ib + 19u, r4, r5, r6, r7);     \
        const f32x4 zz = {0.f,0.f,0.f,0.f};                                    \
        f32x4 d0 = __builtin_amdgcn_mfma_f32_16x16x32_bf16(ka.v, qf.v, zz, 0, 0, 0); \
        f32x4 d1 = __builtin_amdgcn_mfma_f32_16x16x32_bf16(kc.v, qf.v, zz, 0, 0, 0); \
        if (TAIL) {                                                            \
            const int sv = srow + 4 * g;                                       \
            d0.x = (sv + 0  <= t_g) ? d0.x : -1e30f;                           \
            d0.y = (sv + 1  <= t_g) ? d0.y : -1e30f;                           \
            d0.z = (sv + 2  <= t_g) ? d0.z : -1e30f;                           \
            d0.w = (sv + 3  <= t_g) ? d0.w : -1e30f;                           \
            d1.x = (sv + 16 <= t_g) ? d1.x : -1e30f;                           \
            d1.y = (sv + 17 <= t_g) ? d1.y : -1e30f;                           \
            d1.z = (sv + 18 <= t_g) ? d1.z : -1e30f;                           \
            d1.w = (sv + 19 <= t_g) ? d1.w : -1e30f;                           \
        }                                                                      \
        float mx = fmaxf(fmaxf(fmaxf(d0.x, d0.y), fmaxf(d0.z, d0.w)),          \
                         fmaxf(fmaxf(d1.x, d1.y), fmaxf(d1.z, d1.w)));         \
        mx = fmaxf(mx, __shfl_xor(mx, 16));                                    \
        mx = fmaxf(mx, __shfl_xor(mx, 32));                                    \
        const bool up = mx > m + 8.0f;          /* deferred-max rescale */     \
        const float corr = up ? __expf(m - mx) : 1.0f;                         \
        m = up ? mx : m;                                                       \
        l *= corr; acc0 *= corr; acc1 *= corr;                                 \
        float p0 = __expf(d0.x - m), p1 = __expf(d0.y - m);                    \
        float p2 = __expf(d0.z - m), p3 = __expf(d0.w - m);                    \
        float p4 = __expf(d1.x - m), p5 = __expf(d1.y - m);                    \
        float p6 = __expf(d1.z - m), p7 = __expf(d1.w - m);                    \
        if (TAIL) {                                                            \
            const float alive = (srow <= t_g) ? 1.0f : 0.0f;                   \
            p0 *= alive; p1 *= alive; p2 *= alive; p3 *= alive;                \
            p4 *= alive; p5 *= alive; p6 *= alive; p7 *= alive;                \
        }                                                                      \
        float ls = ((p0 + p1) + (p2 + p3)) + ((p4 + p5) + (p6 + p7));          \
        ls += __shfl_xor(ls, 16);                                              \
        ls += __shfl_xor(ls, 32);                                              \
        l += ls;                                                               \
        const float q0 = (r0 < KEEP_LT9) ? p0 : 0.f;   /* direct select */     \
        const float q1 = (r1 < KEEP_LT9) ? p1 : 0.f;                           \
        const float q2 = (r2 < KEEP_LT9) ? p2 : 0.f;                           \
        const float q3 = (r3 < KEEP_LT9) ? p3 : 0.f;                           \
        const float q4 = (r4 < KEEP_LT9) ? p4 : 0.f;                           \
        const float q5 = (r5 < KEEP_LT9) ? p5 : 0.f;                           \
        const float q6 = (r6 < KEEP_LT9) ? p6 : 0.f;                           \
        const float q7 = (r7 < KEEP_LT9) ? p7 : 0.f;                           \
        const uint32_t k00 = cvt_pk_bf16(q0, q1), k01 = cvt_pk_bf16(q2, q3);   \
        const uint32_t k10 = cvt_pk_bf16(q4, q5), k11 = cvt_pk_bf16(q6, q7);   \
        const int srcA = 16 * ((g & 1) * 2) + tl;                              \
        const int srcB = srcA + 16;                                            \
        const uint32_t a0 = (uint32_t)__shfl((int)k00, srcA);                  \
        const uint32_t b0 = (uint32_t)__shfl((int)k10, srcA);                  \
        const uint32_t a1 = (uint32_t)__shfl((int)k01, srcA);                  \
        const uint32_t b1 = (uint32_t)__shfl((int)k11, srcA);                  \
        const uint32_t a2 = (uint32_t)__shfl((int)k00, srcB);                  \
        const uint32_t b2 = (uint32_t)__shfl((int)k10, srcB);                  \
        const uint32_t a3 = (uint32_t)__shfl((int)k01, srcB);                  \
        const uint32_t b3 = (uint32_t)__shfl((int)k11, srcB);                  \
        const bool hi = (g >= 2);                                              \
        pf.u[0] = hi ? b0 : a0; pf.u[1] = hi ? b1 : a1;                        \
        pf.u[2] = hi ? b2 : a2; pf.u[3] = hi ? b3 : a3;                        \
        acc0 = __builtin_amdgcn_mfma_f32_16x16x32_bf16(va.v, pf.v, acc0, 0, 0, 0); \
        acc1 = __builtin_amdgcn_mfma_f32_16x16x32_bf16(vc.v, pf.v, acc1, 0, 0, 0); \
    }

    #pragma unroll 1
    for (int win = 0; win < nwin - 1; ++win) {      // bulk: fully valid
        ATT_WINDOW(win << 7, 0)
    }
    {                                                // tail: causal
        const int s0 = (nwin - 1) << 7;
        if (s0 + slb <= tbase + 15) ATT_WINDOW(s0, 1)
    }
#undef ATT_WINDOW

    // ---- merge the 4 s-slices (2-stage LDS tree) ----
    // slot: acc[16 t][36 c] f32 (2304B) + ml[16][2] (128B) = 2432B; 2 slots
#define SLOT(S) reinterpret_cast<float*>(smem + (S) * 2432)
#define PUBLISH(SB)                                                            \
    {                                                                          \
        float* sb = (SB);                                                      \
        *reinterpret_cast<float4*>(sb + tl * 36 + 4 * g)      = make_float4(acc0.x, acc0.y, acc0.z, acc0.w); \
        *reinterpret_cast<float4*>(sb + tl * 36 + 16 + 4 * g) = make_float4(acc1.x, acc1.y, acc1.z, acc1.w); \
        if (g == 0) { sb[576 + 2 * tl] = m; sb[577 + 2 * tl] = l; }            \
    }
#define CONSUME(SB)                                                            \
    {                                                                          \
        const float* sb = (SB);                                                \
        const float m2 = sb[576 + 2 * tl], l2 = sb[577 + 2 * tl];              \
        const float4 x0 = *reinterpret_cast<const float4*>(sb + tl * 36 + 4 * g); \
        const float4 x1 = *reinterpret_cast<const float4*>(sb + tl * 36 + 16 + 4 * g); \
        const float mn = fmaxf(m, m2);                                         \
        const float ca = __expf(m - mn), cb = __expf(m2 - mn);                 \
        l = l * ca + l2 * cb;                                                  \
        acc0.x = acc0.x * ca + x0.x * cb; acc0.y = acc0.y * ca + x0.y * cb;    \
        acc0.z = acc0.z * ca + x0.z * cb; acc0.w = acc0.w * ca + x0.w * cb;    \
        acc1.x = acc1.x * ca + x1.x * cb; acc1.y = acc1.y * ca + x1.y * cb;    \
        acc1.z = acc1.z * ca + x1.z * cb; acc1.w = acc1.w * ca + x1.w * cb;    \
        m = mn;                                                                \
    }
    if (sg >= 2) PUBLISH(SLOT(sg - 2))
    __syncthreads();
    if (sg < 2) CONSUME(SLOT(sg))
    __syncthreads();
    if (sg == 1) PUBLISH(SLOT(0))
    __syncthreads();
    if (sg == 0) {
        CONSUME(SLOT(0))
        const float inv = 1.0f / (0.8f * l);            // l,t lane-local
        float* orow = out + ((size_t)b * TTN + t_g) * CCH;
        *reinterpret_cast<float4*>(orow + 4 * g) =
            make_float4(acc0.x * inv, acc0.y * inv, acc0.z * inv, acc0.w * inv);
        *reinterpret_cast<float4*>(orow + 16 + 4 * g) =
            make_float4(acc1.x * inv, acc1.y * inv, acc1.z * inv, acc1.w * inv);
    }
#undef SLOT
#undef PUBLISH
#undef CONSUME
}

extern "C" void kernel_launch(void* const* d_in, const int* in_sizes, int n_in,
                              void* d_out, int out_size, void* d_ws, size_t ws_size,
                              hipStream_t stream) {
    const float* x  = (const float*)d_in[0];
    const float* Wq = (const float*)d_in[1];
    const float* Wk = (const float*)d_in[2];
    const float* Wv = (const float*)d_in[3];
    float* outp = (float*)d_out;

    // workspace: Qf fp32 4MiB | Kb bf16 2MiB | Vt bf16 2MiB
    float*    Qf = (float*)d_ws;
    uint16_t* Kb = (uint16_t*)((char*)d_ws + 4194304);
    uint16_t* Vt = (uint16_t*)((char*)d_ws + 6291456);

    proj_qkv<<<(BB * TTN) / 256, 256, 0, stream>>>(x, Wq, Wk, Wv, Qf, Kb, Vt);
    attn_mfma<<<2048, 256, 0, stream>>>(Qf, Kb, Vt, outp);
}

// Round 13
// 164.651 us; speedup vs baseline: 1.0390x; 1.0390x over previous
//
#include <hip/hip_runtime.h>
#include <stdint.h>

#define BB 8
#define TTN 4096
#define CCH 32
#define KEEP_LT9 3435974144u   // keep iff bits < this (uniform < 0.8f)

typedef __attribute__((ext_vector_type(8))) short bf16x8;
typedef __attribute__((ext_vector_type(4))) float f32x4;

union B8 { uint32_t u[4]; uint4 q; bf16x8 v; };

__device__ __forceinline__ uint32_t cvt_pk_bf16(float lo, float hi) {
    uint32_t d;
    asm("v_cvt_pk_bf16_f32 %0, %1, %2" : "=v"(d) : "v"(lo), "v"(hi));
    return d;
}

// bare v_exp_f32: 2^x (scores are kept in log2 domain; no mul needed)
__device__ __forceinline__ float exp2_fast(float x) {
    float d;
    asm("v_exp_f32 %0, %1" : "=v"(d) : "v"(x));
    return d;
}

// rotl via funnel-shift: 1 VALU inst
__device__ __forceinline__ uint32_t rotl32(uint32_t x, int r) {
    return __builtin_amdgcn_alignbit(x, x, 32 - r);
}

// 4 interleaved threefry2x32 chains (explicit ILP; key (0,42); out = o0^o1)
__device__ __forceinline__ void threefry4(uint32_t i0, uint32_t i1, uint32_t i2, uint32_t i3,
                                          uint32_t& o0, uint32_t& o1, uint32_t& o2, uint32_t& o3) {
    const uint32_t K2 = 42u ^ 0x1BD11BDAu;
    uint32_t a0 = 0u, a1 = 0u, a2 = 0u, a3 = 0u;
    uint32_t b0 = i0 + 42u, b1 = i1 + 42u, b2 = i2 + 42u, b3 = i3 + 42u;
#define R4(r)                                                                  \
    { a0 += b0; a1 += b1; a2 += b2; a3 += b3;                                  \
      b0 = rotl32(b0, (r)); b1 = rotl32(b1, (r));                              \
      b2 = rotl32(b2, (r)); b3 = rotl32(b3, (r));                              \
      b0 ^= a0; b1 ^= a1; b2 ^= a2; b3 ^= a3; }
#define INJ(da, db)                                                            \
    { a0 += (da); a1 += (da); a2 += (da); a3 += (da);                          \
      b0 += (db); b1 += (db); b2 += (db); b3 += (db); }
    R4(13) R4(15) R4(26) R4(6)
    INJ(42u, K2 + 1u)
    R4(17) R4(29) R4(16) R4(24)
    INJ(K2, 2u)
    R4(13) R4(15) R4(26) R4(6)
    INJ(0u, 42u + 3u)
    R4(17) R4(29) R4(16) R4(24)
    INJ(42u, K2 + 4u)
    R4(13) R4(15) R4(26) R4(6)
    INJ(K2, 5u)
#undef R4
#undef INJ
    o0 = a0 ^ b0; o1 = a1 ^ b1; o2 = a2 ^ b2; o3 = a3 ^ b3;
}

// ---------------- projections: Q fp32 (scaled to log2 domain), K bf16, V bf16 TRANSPOSED ----------------
__global__ __launch_bounds__(256) void proj_qkv(const float* __restrict__ x,
                                                const float* __restrict__ Wq,
                                                const float* __restrict__ Wk,
                                                const float* __restrict__ Wv,
                                                float* __restrict__ Qf,
                                                uint16_t* __restrict__ Kb,
                                                uint16_t* __restrict__ Vt) {
    __shared__ float sW[3][CCH * CCH];
    __shared__ uint16_t vs[256][34];            // v bf16, padded row (bank spread)
    const int tid = threadIdx.x;
    for (int i = tid; i < CCH * CCH; i += 256) {
        sW[0][i] = Wq[i]; sW[1][i] = Wk[i]; sW[2][i] = Wv[i];
    }
    __syncthreads();
    const int row = blockIdx.x * 256 + tid;     // b*T + t
    const float4* xp = reinterpret_cast<const float4*>(x + (size_t)row * CCH);
    float xr[CCH];
    #pragma unroll
    for (int i = 0; i < 8; ++i) {
        float4 t4 = xp[i];
        xr[4*i] = t4.x; xr[4*i+1] = t4.y; xr[4*i+2] = t4.z; xr[4*i+3] = t4.w;
    }
    const float scale = 0.2550348616f;          // log2(e)/sqrt(32): scores in log2 domain
    #pragma unroll
    for (int mtx = 0; mtx < 3; ++mtx) {
        float o[CCH];
        #pragma unroll
        for (int d = 0; d < CCH; ++d) {
            float s0 = 0.f, s1 = 0.f, s2 = 0.f, s3 = 0.f;
            #pragma unroll
            for (int c = 0; c < CCH; c += 4) {
                s0 += xr[c]   * sW[mtx][d*CCH + c];
                s1 += xr[c+1] * sW[mtx][d*CCH + c+1];
                s2 += xr[c+2] * sW[mtx][d*CCH + c+2];
                s3 += xr[c+3] * sW[mtx][d*CCH + c+3];
            }
            o[d] = (s0 + s1) + (s2 + s3);
            if (mtx == 0) o[d] *= scale;
        }
        if (mtx == 0) {
            float4* op = reinterpret_cast<float4*>(Qf + (size_t)row * CCH);
            #pragma unroll
            for (int i = 0; i < 8; ++i)
                op[i] = make_float4(o[4*i], o[4*i+1], o[4*i+2], o[4*i+3]);
        } else if (mtx == 1) {
            uint32_t dw[16];
            #pragma unroll
            for (int k = 0; k < 16; ++k) dw[k] = cvt_pk_bf16(o[2*k], o[2*k+1]);
            uint4* kp = reinterpret_cast<uint4*>((char*)Kb + (size_t)row * 64);
            #pragma unroll
            for (int q = 0; q < 4; ++q)
                kp[q] = make_uint4(dw[4*q], dw[4*q+1], dw[4*q+2], dw[4*q+3]);
        } else {
            #pragma unroll
            for (int k = 0; k < 16; ++k)
                *reinterpret_cast<uint32_t*>(&vs[tid][2*k]) = cvt_pk_bf16(o[2*k], o[2*k+1]);
        }
    }
    __syncthreads();
    // transpose-out: Vt[b][d][4096] bf16; block covers s-range [seg*256, +255] of batch b
    const int b = blockIdx.x >> 4, seg = blockIdx.x & 15;
    const int d = tid >> 3, part = tid & 7;
    uint32_t dw[16];
    #pragma unroll
    for (int k = 0; k < 16; ++k) {
        const uint32_t lo = vs[part*32 + 2*k][d];
        const uint32_t hi = vs[part*32 + 2*k + 1][d];
        dw[k] = lo | (hi << 16);
    }
    uint16_t* dst = Vt + (size_t)b * (CCH * TTN) + (size_t)d * TTN + seg * 256 + part * 32;
    uint4* dp = reinterpret_cast<uint4*>(dst);
    #pragma unroll
    for (int q = 0; q < 4; ++q)
        dp[q] = make_uint4(dw[4*q], dw[4*q+1], dw[4*q+2], dw[4*q+3]);
}

// ---------------- MFMA flash attention, fused threefry, 1-window software pipeline ----------------
// Block = 256 thr (4 waves = 4 s-slices of 32 within a 128-s window), 16 q-rows.
// Per window: S^T mfma -> m-reduce via same-wave LDS (1 wait) -> exp2 (log2-domain
// scores, bare v_exp) -> dropout select -> P exchange via same-wave LDS b128
// write + 2x8B read (replaces 8 bpermutes) -> PV mfma. l-reduce DEFERRED to end.
// Loads + threefry for window w+1 issued before softmax(w): 576 independent VALU
// insts fill softmax's LDS-wait stalls. LDS: mx 1K | P 4K | merge 4.9K.
__global__ __launch_bounds__(256, 6) void attn_mfma(const float* __restrict__ Qf,
                                                    const uint16_t* __restrict__ Kb,
                                                    const uint16_t* __restrict__ Vt,
                                                    float* __restrict__ out) {
    __shared__ __align__(16) char smem[9984];

    const int j = blockIdx.x;
    const int b = j & 7;                        // XCD-local batch
    const int thalf = (j >> 3) & 1;
    const int tile = 127 - (j >> 4);            // LPT: biggest tiles first

    const int w = threadIdx.x >> 6;             // wave = s-slice 0..3
    const int lane = threadIdx.x & 63;
    const int tl = lane & 15;
    const int g = lane >> 4;
    const int slb = w * 32;
    const int tbase = tile * 32 + thalf * 16;
    const int t_g = tbase + tl;

    // Q fragment (B-operand: col=t=lane&15, k=d=8g+j), bf16 (log2-scaled), loaded once
    const float* qrow = Qf + ((size_t)b * TTN + t_g) * CCH + g * 8;
    const float4 qa = *reinterpret_cast<const float4*>(qrow);
    const float4 qb = *reinterpret_cast<const float4*>(qrow + 4);
    B8 qf;
    qf.u[0] = cvt_pk_bf16(qa.x, qa.y); qf.u[1] = cvt_pk_bf16(qa.z, qa.w);
    qf.u[2] = cvt_pk_bf16(qb.x, qb.y); qf.u[3] = cvt_pk_bf16(qb.z, qb.w);

    f32x4 acc0 = {0.f,0.f,0.f,0.f}, acc1 = {0.f,0.f,0.f,0.f};
    float m = -1e30f, l = 0.f;                  // m in log2 domain; l unreduced per-lane

    const char* Kbb = (const char*)Kb + (size_t)b * TTN * 64;
    const char* Vbb = (const char*)Vt + (size_t)b * CCH * TTN * 2;
    const uint32_t idxb = ((uint32_t)b << 24) | ((uint32_t)t_g << 12);

    const int nwin = ((tbase + 15) >> 7) + 1;

    // LDS regions (per-wave private; no cross-wave use before merge)
    float* mxex = reinterpret_cast<float*>(smem) + (w << 6);            // [64] f32
    uint32_t* pex = reinterpret_cast<uint32_t*>(smem + 1024) + (w << 8); // [256] u32

    B8 kaA, kcA, vaA, vcA, kaB, kcB, vaB, vcB;
    uint32_t rA[8], rB[8];

#define LOADF(KA, KC, VA, VC, S0)                                              \
    {                                                                          \
        const int srow = (S0) + slb;                                           \
        KA.q = *reinterpret_cast<const uint4*>(Kbb + (size_t)(srow + tl) * 64 + g * 16); \
        KC.q = *reinterpret_cast<const uint4*>(Kbb + (size_t)(srow + 16 + tl) * 64 + g * 16); \
        VA.q = *reinterpret_cast<const uint4*>(Vbb + (size_t)tl * 8192 + (size_t)(srow + g * 8) * 2); \
        VC.q = *reinterpret_cast<const uint4*>(Vbb + (size_t)(16 + tl) * 8192 + (size_t)(srow + g * 8) * 2); \
    }
#define TF8(R, S0)                                                             \
    {                                                                          \
        const uint32_t ib = idxb | (uint32_t)((S0) + slb + 4 * g);             \
        threefry4(ib,       ib + 1u,  ib + 2u,  ib + 3u,  R[0], R[1], R[2], R[3]); \
        threefry4(ib + 16u, ib + 17u, ib + 18u, ib + 19u, R[4], R[5], R[6], R[7]); \
    }
#define SMAXPV(S0, TAIL)                                                       \
    {                                                                          \
        const f32x4 zz = {0.f,0.f,0.f,0.f};                                    \
        f32x4 d0 = __builtin_amdgcn_mfma_f32_16x16x32_bf16(kaA.v, qf.v, zz, 0, 0, 0); \
        f32x4 d1 = __builtin_amdgcn_mfma_f32_16x16x32_bf16(kcA.v, qf.v, zz, 0, 0, 0); \
        if (TAIL) {                                                            \
            const int sv = (S0) + slb + 4 * g;                                 \
            d0.x = (sv + 0  <= t_g) ? d0.x : -1e30f;                           \
            d0.y = (sv + 1  <= t_g) ? d0.y : -1e30f;                           \
            d0.z = (sv + 2  <= t_g) ? d0.z : -1e30f;                           \
            d0.w = (sv + 3  <= t_g) ? d0.w : -1e30f;                           \
            d1.x = (sv + 16 <= t_g) ? d1.x : -1e30f;                           \
            d1.y = (sv + 17 <= t_g) ? d1.y : -1e30f;                           \
            d1.z = (sv + 18 <= t_g) ? d1.z : -1e30f;                           \
            d1.w = (sv + 19 <= t_g) ? d1.w : -1e30f;                           \
        }                                                                      \
        float mx = fmaxf(fmaxf(fmaxf(d0.x, d0.y), fmaxf(d0.z, d0.w)),          \
                         fmaxf(fmaxf(d1.x, d1.y), fmaxf(d1.z, d1.w)));         \
        mxex[(tl << 2) + g] = mx;                        /* same-wave LDS */   \
        const float4 m4 = *reinterpret_cast<const float4*>(mxex + (tl << 2));  \
        mx = fmaxf(fmaxf(m4.x, m4.y), fmaxf(m4.z, m4.w));                      \
        const bool up = mx > m + 11.5f;         /* deferred-max, log2 units */ \
        const float corr = up ? exp2_fast(m - mx) : 1.0f;                      \
        m = up ? mx : m;                                                       \
        l *= corr; acc0 *= corr; acc1 *= corr;                                 \
        float p0 = exp2_fast(d0.x - m), p1 = exp2_fast(d0.y - m);              \
        float p2 = exp2_fast(d0.z - m), p3 = exp2_fast(d0.w - m);              \
        float p4 = exp2_fast(d1.x - m), p5 = exp2_fast(d1.y - m);              \
        float p6 = exp2_fast(d1.z - m), p7 = exp2_fast(d1.w - m);              \
        if (TAIL) {                                                            \
            const float alive = ((S0) + slb <= t_g) ? 1.0f : 0.0f;             \
            p0 *= alive; p1 *= alive; p2 *= alive; p3 *= alive;                \
            p4 *= alive; p5 *= alive; p6 *= alive; p7 *= alive;                \
        }                                                                      \
        l += ((p0 + p1) + (p2 + p3)) + ((p4 + p5) + (p6 + p7));                \
        const float q0 = (rA[0] < KEEP_LT9) ? p0 : 0.f;                        \
        const float q1 = (rA[1] < KEEP_LT9) ? p1 : 0.f;                        \
        const float q2 = (rA[2] < KEEP_LT9) ? p2 : 0.f;                        \
        const float q3 = (rA[3] < KEEP_LT9) ? p3 : 0.f;                        \
        const float q4 = (rA[4] < KEEP_LT9) ? p4 : 0.f;                        \
        const float q5 = (rA[5] < KEEP_LT9) ? p5 : 0.f;                        \
        const float q6 = (rA[6] < KEEP_LT9) ? p6 : 0.f;                        \
        const float q7 = (rA[7] < KEEP_LT9) ? p7 : 0.f;                        \
        const uint32_t k00 = cvt_pk_bf16(q0, q1), k01 = cvt_pk_bf16(q2, q3);   \
        const uint32_t k10 = cvt_pk_bf16(q4, q5), k11 = cvt_pk_bf16(q6, q7);   \
        *reinterpret_cast<uint4*>(pex + (lane << 2)) = make_uint4(k00, k01, k10, k11); \
        const int srcA4 = (((g & 1) ? 32 : 0) + tl) << 2;                      \
        const int sel = (g >= 2) ? 2 : 0;                                      \
        const uint2 lo2 = *reinterpret_cast<const uint2*>(pex + srcA4 + sel);  \
        const uint2 hi2 = *reinterpret_cast<const uint2*>(pex + srcA4 + 64 + sel); \
        B8 pf;                                                                 \
        pf.u[0] = lo2.x; pf.u[1] = lo2.y; pf.u[2] = hi2.x; pf.u[3] = hi2.y;    \
        acc0 = __builtin_amdgcn_mfma_f32_16x16x32_bf16(vaA.v, pf.v, acc0, 0, 0, 0); \
        acc1 = __builtin_amdgcn_mfma_f32_16x16x32_bf16(vcA.v, pf.v, acc1, 0, 0, 0); \
    }

    LOADF(kaA, kcA, vaA, vcA, 0)
    TF8(rA, 0)
    #pragma unroll 1
    for (int win = 0; win < nwin - 1; ++win) {
        LOADF(kaB, kcB, vaB, vcB, (win + 1) << 7)   // next-window frags
        TF8(rB, (win + 1) << 7)                     // 576 indep VALU: fills stalls
        SMAXPV(win << 7, 0)
        kaA = kaB; kcA = kcB; vaA = vaB; vcA = vcB;
        #pragma unroll
        for (int i = 0; i < 8; ++i) rA[i] = rB[i];
    }
    {                                                // tail: causal
        const int s0 = (nwin - 1) << 7;
        if (s0 + slb <= tbase + 15) SMAXPV(s0, 1)
    }
#undef SMAXPV
#undef TF8
#undef LOADF

    // deferred l-reduce over the 4 g-lanes of each t
    l += __shfl_xor(l, 16);
    l += __shfl_xor(l, 32);

    // ---- merge the 4 s-slices (2-stage LDS tree) ----
#define SLOT(S) reinterpret_cast<float*>(smem + 5120 + (S) * 2432)
#define PUBLISH(SB)                                                            \
    {                                                                          \
        float* sb = (SB);                                                      \
        *reinterpret_cast<float4*>(sb + tl * 36 + 4 * g)      = make_float4(acc0.x, acc0.y, acc0.z, acc0.w); \
        *reinterpret_cast<float4*>(sb + tl * 36 + 16 + 4 * g) = make_float4(acc1.x, acc1.y, acc1.z, acc1.w); \
        if (g == 0) { sb[576 + 2 * tl] = m; sb[577 + 2 * tl] = l; }            \
    }
#define CONSUME(SB)                                                            \
    {                                                                          \
        const float* sb = (SB);                                                \
        const float m2 = sb[576 + 2 * tl], l2 = sb[577 + 2 * tl];              \
        const float4 x0 = *reinterpret_cast<const float4*>(sb + tl * 36 + 4 * g); \
        const float4 x1 = *reinterpret_cast<const float4*>(sb + tl * 36 + 16 + 4 * g); \
        const float mn = fmaxf(m, m2);                                         \
        const float ca = exp2_fast(m - mn), cb = exp2_fast(m2 - mn);           \
        l = l * ca + l2 * cb;                                                  \
        acc0.x = acc0.x * ca + x0.x * cb; acc0.y = acc0.y * ca + x0.y * cb;    \
        acc0.z = acc0.z * ca + x0.z * cb; acc0.w = acc0.w * ca + x0.w * cb;    \
        acc1.x = acc1.x * ca + x1.x * cb; acc1.y = acc1.y * ca + x1.y * cb;    \
        acc1.z = acc1.z * ca + x1.z * cb; acc1.w = acc1.w * ca + x1.w * cb;    \
        m = mn;                                                                \
    }
    if (w >= 2) PUBLISH(SLOT(w - 2))
    __syncthreads();
    if (w < 2) CONSUME(SLOT(w))
    __syncthreads();
    if (w == 1) PUBLISH(SLOT(0))
    __syncthreads();
    if (w == 0) {
        CONSUME(SLOT(0))
        const float inv = 1.0f / (0.8f * l);            // l,t lane-local
        float* orow = out + ((size_t)b * TTN + t_g) * CCH;
        *reinterpret_cast<float4*>(orow + 4 * g) =
            make_float4(acc0.x * inv, acc0.y * inv, acc0.z * inv, acc0.w * inv);
        *reinterpret_cast<float4*>(orow + 16 + 4 * g) =
            make_float4(acc1.x * inv, acc1.y * inv, acc1.z * inv, acc1.w * inv);
    }
#undef SLOT
#undef PUBLISH
#undef CONSUME
}

extern "C" void kernel_launch(void* const* d_in, const int* in_sizes, int n_in,
                              void* d_out, int out_size, void* d_ws, size_t ws_size,
                              hipStream_t stream) {
    const float* x  = (const float*)d_in[0];
    const float* Wq = (const float*)d_in[1];
    const float* Wk = (const float*)d_in[2];
    const float* Wv = (const float*)d_in[3];
    float* outp = (float*)d_out;

    // workspace: Qf fp32 4MiB | Kb bf16 2MiB | Vt bf16 2MiB
    float*    Qf = (float*)d_ws;
    uint16_t* Kb = (uint16_t*)((char*)d_ws + 4194304);
    uint16_t* Vt = (uint16_t*)((char*)d_ws + 6291456);

    proj_qkv<<<(BB * TTN) / 256, 256, 0, stream>>>(x, Wq, Wk, Wv, Qf, Kb, Vt);
    attn_mfma<<<2048, 256, 0, stream>>>(Qf, Kb, Vt, outp);
}